// Round 3
// baseline (396.613 us; speedup 1.0000x reference)
//
#include <hip/hip_runtime.h>
#include <stdint.h>
#include <math.h>

#define SS 8
#define NBLK 8192
#define DIN 512
#define DOUT 256
#define GB 8              // graph blocks per WG
#define MT 64             // rows per WG
#define BK 32             // K chunk
#define KSTEPS 16         // DIN/BK
#define VSTR 264          // anchor bf16 LDS stride
#define EPSN 1e-12f

typedef __bf16 bf16;
typedef __bf16 bf16x8 __attribute__((ext_vector_type(8)));
typedef float  f32x4  __attribute__((ext_vector_type(4)));

typedef __attribute__((address_space(3))) uint32_t       lds_u32;
typedef __attribute__((address_space(1))) const uint32_t g_u32;

__device__ __forceinline__ void dma16(const void* g, void* l) {
    // async global->LDS, 16 B per lane; LDS dest = wave-uniform base + lane*16
    __builtin_amdgcn_global_load_lds((g_u32*)g, (lds_u32*)l, 16, 0, 0);
}

__device__ __forceinline__ bf16x8 cvt8(f32x4 lo, f32x4 hi) {
    bf16x8 r;
    r[0] = (bf16)lo[0]; r[1] = (bf16)lo[1]; r[2] = (bf16)lo[2]; r[3] = (bf16)lo[3];
    r[4] = (bf16)hi[0]; r[5] = (bf16)hi[1]; r[6] = (bf16)hi[2]; r[7] = (bf16)hi[3];
    return r;
}

// ---- prep: Wt = W_gcn^T in bf16, K-STEP-TILED layout Wt[s][n][kk]
//      (s = k/32, kk = k%32): per-wave per-step B slice is contiguous ----
__global__ void prep_kernel(const float* __restrict__ W_gcn,
                            const float* __restrict__ W_bil,
                            bf16* __restrict__ Wt,
                            bf16* __restrict__ Wh,
                            bf16* __restrict__ Wl) {
    int idx = blockIdx.x * 256 + threadIdx.x;   // 196608 total
    if (idx < DIN * DOUT) {
        int k = idx >> 8, n = idx & 255;
        Wt[((size_t)(k >> 5) * DOUT + n) * BK + (k & 31)] = (bf16)W_gcn[idx];
    } else {
        int j = idx - DIN * DOUT;               // < 65536
        float wv = W_bil[j];
        bf16 h = (bf16)wv;
        Wh[j] = h;
        Wl[j] = (bf16)(wv - (float)h);
    }
}

// Branch-split: 512 threads, 8 waves. Waves 0-3 = pos branch, 4-7 = neg branch;
// wave handles its 64-col quarter over all 64 rows of ITS branch only.
// acc = 64 regs/wave (was 128) -> __launch_bounds__(512,4) = 2 blocks/CU
// = 16 waves/CU = 4 waves/SIMD (was 2). A staged via async DMA into a 3-stage
// ring with counted vmcnt(2); B (step-tiled Wt) double-buffered in registers.
__global__ __launch_bounds__(512, 4) void cola_fused7(
    const float* __restrict__ pos_x, const float* __restrict__ neg_x,
    const int* __restrict__ pos_src, const int* __restrict__ pos_dst,
    const float* __restrict__ pos_w,
    const int* __restrict__ neg_src, const int* __restrict__ neg_dst,
    const float* __restrict__ neg_w,
    const bf16* __restrict__ Wt, const bf16* __restrict__ Wh,
    const bf16* __restrict__ Wl,
    const float* __restrict__ b_gcn, const float* __restrict__ prelu_a,
    const float* __restrict__ b_bil, float* __restrict__ out)
{
    __shared__ __align__(16) float bufA[3][2][MT * BK];   // 3 stages x (pos,neg), 48 KB
    __shared__ float adjP[GB][SS][SS];                    // 2 KB
    __shared__ float adjN[GB][SS][SS];                    // 2 KB
    __shared__ float red[5 * GB];                         // ssqP|ssqA|ssqN|scoreP|scoreN

    // epilogue buffers aliased onto bufA stages (dead after K-loop + barrier)
    float* pool_pos = (float*)&bufA[0][0][0];             // 8 KB (stage 0, pos half)
    float* v_lds    = pool_pos + GB * DOUT;               // 8 KB (stage 0, neg half)
    bf16*  ahs      = (bf16*)&bufA[1][0][0];              // 4.125 KB (stage 1)
    bf16*  als      = ahs + GB * VSTR;                    // 4.125 KB

    const int t    = threadIdx.x;
    const int wg   = blockIdx.x;
    const int w    = t >> 6;          // 0..7
    const int b    = w >> 2;          // 0 = pos, 1 = neg
    const int wq   = w & 3;           // col quarter
    const int lane = t & 63;
    const int q    = lane >> 4;
    const int r15  = lane & 15;
    const int row0 = wg * MT;

    // ---- zero adjacency + reductions ----
    for (int i = t; i < GB * 64; i += 512) { ((float*)adjP)[i] = 0.f; ((float*)adjN)[i] = 0.f; }
    if (t < 5 * GB) red[t] = 0.f;
    __syncthreads();

    // ---- build weighted adjacency (512 edges/branch per WG, 1 per thread) ----
    {
        int   sp = pos_src[wg * 512 + t];
        int   dp = pos_dst[wg * 512 + t];
        float wp = pos_w[wg * 512 + t];
        int   sn = neg_src[wg * 512 + t];
        int   dn = neg_dst[wg * 512 + t];
        float wn = neg_w[wg * 512 + t];
        int gl = t >> 6;
        int base = (wg * GB + gl) * SS;
        atomicAdd(&adjP[gl][dp - base][sp - base], wp);
        atomicAdd(&adjN[gl][dn - base][sn - base], wn);
    }
    // adj LDS-atomic visibility covered by first K-loop lgkmcnt(0)+barrier

    // ---- DMA lane mapping (A) ----
    // chunk c covers rows c*8..c*8+7; lane: row = c*8+(lane>>3),
    // stored k-quarter = lane&7 holds actual quarter (lane&7)^(lane>>3) (XOR swizzle)
    const int arow_off = lane >> 3;                 // 0..7
    const int akq      = (lane & 7) ^ arow_off;     // actual global quarter to fetch
    const float* xb    = (b == 0) ? pos_x : neg_x;  // this wave's branch input

    auto issueA = [&](int s, int bufi) {
        const int kbase = s * BK;
#pragma unroll
        for (int h = 0; h < 2; ++h) {
            int c = wq * 2 + h;                     // 4 waves/branch x 2 = chunks 0..7
            int row = c * 8 + arow_off;
            dma16(xb + (size_t)(row0 + row) * DIN + kbase + akq * 4,
                  &bufA[bufi][b][c * 256]);
        }
    };

    // B: step-tiled Wt; wave's col quarter, fragment ni -> one contiguous load
    auto loadB = [&](bf16x8* dst, int s) {
#pragma unroll
        for (int ni = 0; ni < 4; ++ni)
            dst[ni] = *(const bf16x8*)(Wt +
                ((size_t)s * DOUT + wq * 64 + ni * 16 + r15) * BK + q * 8);
    };

    f32x4 acc[4][4];
#pragma unroll
    for (int mi = 0; mi < 4; ++mi)
#pragma unroll
        for (int ni = 0; ni < 4; ++ni)
            acc[mi][ni] = (f32x4){0.f, 0.f, 0.f, 0.f};

    bf16x8 breg[2][4];

    // ---- prologue: A(0), B(0), A(1) ----
    issueA(0, 0);
    loadB(breg[0], 0);
    issueA(1, 1);

    // ================= K-loop: counted vmcnt + raw barrier, 3-stage A ring ====
    // Per-wave queue at iter-s wait (old->new): [B(s)x4, A(s+1)x2]
    //   -> vmcnt(2) guarantees A(s),B(s) landed, keeps A(s+1) in flight.
#pragma unroll
    for (int s = 0; s < KSTEPS; ++s) {
        if (s == KSTEPS - 1)
            asm volatile("s_waitcnt vmcnt(0) lgkmcnt(0)" ::: "memory");
        else
            asm volatile("s_waitcnt vmcnt(2) lgkmcnt(0)" ::: "memory");
        __builtin_amdgcn_s_barrier();
        __builtin_amdgcn_sched_barrier(0);

        if (s + 1 < KSTEPS) loadB(breg[(s + 1) & 1], s + 1);
        if (s + 2 < KSTEPS) issueA(s + 2, (s + 2) % 3);

        const int bufi = s % 3;
        const bf16x8* bfv = breg[s & 1];
        const int q0 = (2 * q) ^ (r15 & 7);      // stored quarter holding j=0..3
        const int q1 = q0 ^ 1;                   // stored quarter holding j=4..7
        bf16x8 af[4];
#pragma unroll
        for (int mi = 0; mi < 4; ++mi) {
            int m = mi * 16 + r15;
            f32x4 lo = *(const f32x4*)&bufA[bufi][b][m * BK + q0 * 4];
            f32x4 hi = *(const f32x4*)&bufA[bufi][b][m * BK + q1 * 4];
            af[mi] = cvt8(lo, hi);
        }
#pragma unroll
        for (int mi = 0; mi < 4; ++mi)
#pragma unroll
            for (int ni = 0; ni < 4; ++ni)
                acc[mi][ni] = __builtin_amdgcn_mfma_f32_16x16x32_bf16(
                    af[mi], bfv[ni], acc[mi][ni], 0, 0, 0);
    }
    __syncthreads();    // all bufA reads done before epilogue aliasing writes

    const float pa = *prelu_a;

    // ================= POS epilogue (waves 0-3, acc = pos) =================
    if (w < 4) {
#pragma unroll
        for (int mi = 0; mi < 4; ++mi) {
            const int gl = mi * 2 + (q >> 1);
            float part = 0.f;
#pragma unroll
            for (int ni = 0; ni < 4; ++ni) {
                float r0, r1, r2, r3, r4, r5, r6, r7;
#pragma unroll
                for (int r = 0; r < 4; ++r) {
                    float own = acc[mi][ni][r];
                    float oth = __shfl_xor(own, 16);
                    float lo = ((q & 1) == 0) ? own : oth;
                    float hi = ((q & 1) == 0) ? oth : own;
                    if (r == 0) { r0 = lo; r4 = hi; }
                    else if (r == 1) { r1 = lo; r5 = hi; }
                    else if (r == 2) { r2 = lo; r6 = hi; }
                    else            { r3 = lo; r7 = hi; }
                }
                int c = wq * 64 + ni * 16 + r15;
                float bg = b_gcn[c];
                float pool = 0.f, anch = 0.f;
#pragma unroll
                for (int d = 0; d < 8; ++d) {
                    const float* ar = &adjP[gl][d][0];
                    float a = bg + ar[0]*r0 + ar[1]*r1 + ar[2]*r2 + ar[3]*r3
                                 + ar[4]*r4 + ar[5]*r5 + ar[6]*r6 + ar[7]*r7;
                    float h = (a >= 0.f) ? a : pa * a;
                    if (d < 7) pool += h; else anch = h;
                }
                float pl = pool * (1.f / 7.f);
                if ((q & 1) == 0) {
                    pool_pos[gl * DOUT + c] = pl;
                    part += pl * pl;
                } else {
                    bf16 hh = (bf16)anch;
                    ahs[gl * VSTR + c] = hh;
                    als[gl * VSTR + c] = (bf16)(anch - (float)hh);
                    part += anch * anch;
                }
            }
            part += __shfl_xor(part, 8);
            part += __shfl_xor(part, 4);
            part += __shfl_xor(part, 2);
            part += __shfl_xor(part, 1);
            if (r15 == 0) atomicAdd((q & 1) ? &red[GB + gl] : &red[gl], part);
        }
    }
    __syncthreads();

    // ===== v = W_bil . anchor (3-term bf16 split MFMA), all 8 waves ==========
    {
        f32x4 accv[2];
        accv[0] = (f32x4){0.f, 0.f, 0.f, 0.f};
        accv[1] = (f32x4){0.f, 0.f, 0.f, 0.f};
        const int ga = (r15 & 7) * VSTR;        // rows 8..15 duplicate 0..7
#pragma unroll
        for (int ks = 0; ks < 8; ++ks) {
            bf16x8 ah_f = *(const bf16x8*)(ahs + ga + ks * 32 + q * 8);
            bf16x8 al_f = *(const bf16x8*)(als + ga + ks * 32 + q * 8);
#pragma unroll
            for (int ni = 0; ni < 2; ++ni) {
                int d = w * 32 + ni * 16 + r15;
                bf16x8 bh = *(const bf16x8*)(Wh + (size_t)d * DOUT + ks * 32 + q * 8);
                bf16x8 bl = *(const bf16x8*)(Wl + (size_t)d * DOUT + ks * 32 + q * 8);
                accv[ni] = __builtin_amdgcn_mfma_f32_16x16x32_bf16(ah_f, bh, accv[ni], 0, 0, 0);
                accv[ni] = __builtin_amdgcn_mfma_f32_16x16x32_bf16(al_f, bh, accv[ni], 0, 0, 0);
                accv[ni] = __builtin_amdgcn_mfma_f32_16x16x32_bf16(ah_f, bl, accv[ni], 0, 0, 0);
            }
        }
        float sp[4] = {0.f, 0.f, 0.f, 0.f};
        if (q < 2) {
#pragma unroll
            for (int ni = 0; ni < 2; ++ni) {
                int c = w * 32 + ni * 16 + r15;
#pragma unroll
                for (int r = 0; r < 4; ++r) {
                    int g = q * 4 + r;
                    v_lds[g * DOUT + c] = accv[ni][r];
                    sp[r] += accv[ni][r] * pool_pos[g * DOUT + c];
                }
            }
        }
#pragma unroll
        for (int r = 0; r < 4; ++r) {
            sp[r] += __shfl_xor(sp[r], 8);
            sp[r] += __shfl_xor(sp[r], 4);
            sp[r] += __shfl_xor(sp[r], 2);
            sp[r] += __shfl_xor(sp[r], 1);
        }
        if (q < 2 && r15 == 0) {
#pragma unroll
            for (int r = 0; r < 4; ++r) atomicAdd(&red[3 * GB + q * 4 + r], sp[r]);
        }
    }
    __syncthreads();

    // ================= NEG epilogue (waves 4-7, acc = neg) ====================
    if (w >= 4) {
#pragma unroll
        for (int mi = 0; mi < 4; ++mi) {
            const int gl = mi * 2 + (q >> 1);
            float part = 0.f;
#pragma unroll
            for (int ni = 0; ni < 4; ++ni) {
                float r0, r1, r2, r3, r4, r5, r6, r7;
#pragma unroll
                for (int r = 0; r < 4; ++r) {
                    float own = acc[mi][ni][r];
                    float oth = __shfl_xor(own, 16);
                    float lo = ((q & 1) == 0) ? own : oth;
                    float hi = ((q & 1) == 0) ? oth : own;
                    if (r == 0) { r0 = lo; r4 = hi; }
                    else if (r == 1) { r1 = lo; r5 = hi; }
                    else if (r == 2) { r2 = lo; r6 = hi; }
                    else            { r3 = lo; r7 = hi; }
                }
                int c = wq * 64 + ni * 16 + r15;
                float bg = b_gcn[c];
                float pool = 0.f;
#pragma unroll
                for (int d = 0; d < 7; ++d) {
                    const float* ar = &adjN[gl][d][0];
                    float a = bg + ar[0]*r0 + ar[1]*r1 + ar[2]*r2 + ar[3]*r3
                                 + ar[4]*r4 + ar[5]*r5 + ar[6]*r6 + ar[7]*r7;
                    float h = (a >= 0.f) ? a : pa * a;
                    pool += h;
                }
                float pl = pool * (1.f / 7.f);
                part += ((q & 1) == 0) ? pl * v_lds[gl * DOUT + c] : pl * pl;
            }
            part += __shfl_xor(part, 8);
            part += __shfl_xor(part, 4);
            part += __shfl_xor(part, 2);
            part += __shfl_xor(part, 1);
            if (r15 == 0) atomicAdd((q & 1) ? &red[2 * GB + gl] : &red[4 * GB + gl], part);
        }
    }
    __syncthreads();

    // ================= finalize ===============================================
    if (t < GB) {
        float np = fmaxf(sqrtf(red[t]), EPSN);
        float na = fmaxf(sqrtf(red[GB + t]), EPSN);
        float nn = fmaxf(sqrtf(red[2 * GB + t]), EPSN);
        float bb = b_bil[0];
        out[wg * GB + t]        = red[3 * GB + t] / (np * na) + bb;
        out[NBLK + wg * GB + t] = red[4 * GB + t] / (nn * na) + bb;
    }
}

extern "C" void kernel_launch(void* const* d_in, const int* in_sizes, int n_in,
                              void* d_out, int out_size, void* d_ws, size_t ws_size,
                              hipStream_t stream) {
    const float* pos_x   = (const float*)d_in[0];
    const float* neg_x   = (const float*)d_in[1];
    const int*   pos_src = (const int*)d_in[2];
    const int*   pos_dst = (const int*)d_in[3];
    const float* pos_w   = (const float*)d_in[4];
    const int*   neg_src = (const int*)d_in[5];
    const int*   neg_dst = (const int*)d_in[6];
    const float* neg_w   = (const float*)d_in[7];
    const float* W_gcn   = (const float*)d_in[8];
    const float* b_gcn   = (const float*)d_in[9];
    const float* prelu_a = (const float*)d_in[10];
    const float* W_bil   = (const float*)d_in[11];
    const float* b_bil   = (const float*)d_in[12];
    float* outp = (float*)d_out;

    bf16* Wt = (bf16*)d_ws;                 // 256 KB (step-tiled)
    bf16* Wh = Wt + DIN * DOUT;             // 128 KB
    bf16* Wl = Wh + DOUT * DOUT;            // 128 KB

    prep_kernel<<<(DIN * DOUT + DOUT * DOUT) / 256, 256, 0, stream>>>(W_gcn, W_bil, Wt, Wh, Wl);
    cola_fused7<<<NBLK / GB, 512, 0, stream>>>(
        pos_x, neg_x, pos_src, pos_dst, pos_w, neg_src, neg_dst, neg_w,
        Wt, Wh, Wl, b_gcn, prelu_a, b_bil, outp);
}

// Round 4
// 389.158 us; speedup vs baseline: 1.0192x; 1.0192x over previous
//
#include <hip/hip_runtime.h>
#include <stdint.h>
#include <math.h>

#define SS 8
#define NBLK 8192
#define DIN 512
#define DOUT 256
#define GB 4              // graph blocks per WG
#define MT 32             // rows per WG
#define BK 32             // K chunk
#define KSTEPS 16         // DIN/BK
#define VSTR 264          // anchor bf16 LDS stride
#define EPSN 1e-12f

typedef __bf16 bf16;
typedef __bf16 bf16x8 __attribute__((ext_vector_type(8)));
typedef float  f32x4  __attribute__((ext_vector_type(4)));

typedef __attribute__((address_space(3))) uint32_t       lds_u32;
typedef __attribute__((address_space(1))) const uint32_t g_u32;

__device__ __forceinline__ void dma16(const void* g, void* l) {
    // async global->LDS, 16 B per lane; LDS dest = wave-uniform base + lane*16,
    // global source address is PER-LANE.
    __builtin_amdgcn_global_load_lds((g_u32*)g, (lds_u32*)l, 16, 0, 0);
}

__device__ __forceinline__ bf16x8 cvt8(f32x4 lo, f32x4 hi) {
    bf16x8 r;
    r[0] = (bf16)lo[0]; r[1] = (bf16)lo[1]; r[2] = (bf16)lo[2]; r[3] = (bf16)lo[3];
    r[4] = (bf16)hi[0]; r[5] = (bf16)hi[1]; r[6] = (bf16)hi[2]; r[7] = (bf16)hi[3];
    return r;
}

// ---- prep ----
// WtImg: W_gcn^T in bf16, FRAGMENT-REGISTER order: for K-step s, col-quarter wq,
// fragment ni, lane l=(q*16+r15), j=0..7:
//   WtImg[(((s*4+wq)*4+ni)*64 + l)*8 + j] = W_gcn[k = s*32+q*8+j][n = wq*64+ni*16+r15]
// A linear DMA of 1 KB chunks then reproduces the exact MFMA B-fragment image in
// LDS; reads are ds_read_b128 at lane*16 (conflict-free).
// Wh/Wl: W_bil split into bf16 hi+lo.
__global__ void prep_kernel(const float* __restrict__ W_gcn,
                            const float* __restrict__ W_bil,
                            bf16* __restrict__ WtImg,
                            bf16* __restrict__ Wh,
                            bf16* __restrict__ Wl) {
    int idx = blockIdx.x * 256 + threadIdx.x;   // 196608 total
    if (idx < DIN * DOUT) {
        int k = idx >> 8, n = idx & 255;
        int s  = k >> 5;
        int qq = (k >> 3) & 3;
        int j  = k & 7;
        int wq = n >> 6;
        int ni = (n >> 4) & 3;
        int r  = n & 15;
        int l  = qq * 16 + r;
        size_t pos = ((size_t)(((s * 4 + wq) * 4 + ni) * 64) + l) * 8 + j;
        WtImg[pos] = (bf16)W_gcn[idx];
    } else {
        int j = idx - DIN * DOUT;               // < 65536
        float wv = W_bil[j];
        bf16 h = (bf16)wv;
        Wh[j] = h;
        Wl[j] = (bf16)(wv - (float)h);
    }
}

// 512 threads, 8 waves, branch-split: waves 0-3 pos, 4-7 neg; wave owns its
// 64-col quarter over the WG's 32 rows (4 graph blocks). acc = 32 regs/wave.
// A: async DMA, 3-stage ring (24 KB). B: async DMA of fragment-order WtImg,
// 2-stage (32 KB), conflict-free ds_read_b128. Counted vmcnt(1) + raw barrier.
// __launch_bounds__(512,4): 4 waves/SIMD = 2 WGs/CU, 128 unified regs/wave.
__global__ __launch_bounds__(512, 4) void cola_fused8(
    const float* __restrict__ pos_x, const float* __restrict__ neg_x,
    const int* __restrict__ pos_src, const int* __restrict__ pos_dst,
    const float* __restrict__ pos_w,
    const int* __restrict__ neg_src, const int* __restrict__ neg_dst,
    const float* __restrict__ neg_w,
    const bf16* __restrict__ WtImg, const bf16* __restrict__ Wh,
    const bf16* __restrict__ Wl,
    const float* __restrict__ b_gcn, const float* __restrict__ prelu_a,
    const float* __restrict__ b_bil, float* __restrict__ out)
{
    __shared__ __align__(16) float bufA[3][2][MT * BK];   // 3 x (pos,neg) x 4 KB = 24 KB
    __shared__ __align__(16) bf16  bufB[2][16 * 512];     // 2 x 16 KB = 32 KB
    __shared__ float adjP[GB][SS][SS];                    // 1 KB
    __shared__ float adjN[GB][SS][SS];                    // 1 KB
    __shared__ float red[5 * GB];                         // ssqP|ssqA|ssqN|scoreP|scoreN

    // epilogue buffers aliased onto dead bufA stages after the K-loop
    float* pool_pos = (float*)&bufA[0][0][0];             // 4 KB (stage 0, first half)
    float* v_lds    = pool_pos + GB * DOUT;               // 4 KB (stage 0, second half)
    bf16*  ahs      = (bf16*)&bufA[1][0][0];              // 2.06 KB (stage 1)
    bf16*  als      = ahs + GB * VSTR;                    // 2.06 KB

    const int t    = threadIdx.x;
    const int wg   = blockIdx.x;
    const int w    = t >> 6;          // 0..7
    const int b    = w >> 2;          // 0 = pos, 1 = neg
    const int wq   = w & 3;           // col quarter
    const int lane = t & 63;
    const int q    = lane >> 4;
    const int r15  = lane & 15;
    const int row0 = wg * MT;

    // ---- zero adjacency + reductions ----
    if (t < GB * 64) { ((float*)adjP)[t] = 0.f; ((float*)adjN)[t] = 0.f; }
    if (t < 5 * GB) red[t] = 0.f;
    __syncthreads();

    // ---- build weighted adjacency (256 edges/branch per WG) ----
    {
        int e  = t & 255;             // edge within WG
        int br = t >> 8;              // 0 = pos, 1 = neg
        const int*   srcA = br ? neg_src : pos_src;
        const int*   dstA = br ? neg_dst : pos_dst;
        const float* wA   = br ? neg_w   : pos_w;
        float* adj = br ? &adjN[0][0][0] : &adjP[0][0][0];
        int   sv = srcA[wg * 256 + e];
        int   dv = dstA[wg * 256 + e];
        float wv = wA[wg * 256 + e];
        int gl = e >> 6;
        int base = (wg * GB + gl) * SS;
        atomicAdd(&adj[gl * 64 + (dv - base) * SS + (sv - base)], wv);
    }
    // adj LDS-atomic visibility covered by first K-loop lgkmcnt(0)+barrier

    // ---- A DMA lane mapping ----
    // wave's chunk = its wq: rows wq*8..wq*8+7 of its branch.
    // lane: row = wq*8+(lane>>3); stored k-quarter (lane&7) holds actual quarter
    // (lane&7)^(lane>>3)  (XOR swizzle -> spread ds_read banks)
    const int arow_off = lane >> 3;                 // 0..7
    const int akq      = (lane & 7) ^ arow_off;     // actual global quarter to fetch
    const float* xb    = (b == 0) ? pos_x : neg_x;  // this wave's branch input

    auto issueA = [&](int s, int bufi) {
        int row = wq * 8 + arow_off;
        dma16(xb + (size_t)(row0 + row) * DIN + s * BK + akq * 4,
              &bufA[bufi][b][wq * 256]);
    };
    // B: wave w loads chunks 2w, 2w+1 of the 16-chunk (16 KB) step image
    auto issueB = [&](int s, int bufi) {
#pragma unroll
        for (int h = 0; h < 2; ++h) {
            int c = w * 2 + h;
            dma16(WtImg + ((size_t)s * 16 + c) * 512 + lane * 8,
                  &bufB[bufi][c * 512]);
        }
    };

    f32x4 acc[2][4];
#pragma unroll
    for (int mi = 0; mi < 2; ++mi)
#pragma unroll
        for (int ni = 0; ni < 4; ++ni)
            acc[mi][ni] = (f32x4){0.f, 0.f, 0.f, 0.f};

    // ---- prologue: A(0), B(0), A(1)  (queue: A0,B0,B0,A1) ----
    issueA(0, 0);
    issueB(0, 0);
    issueA(1, 1);

    // ================= K-loop =================================================
    // Per-wave queue at iter-s wait (old->new): [B(s)x2, A(s+1)x1]
    //   -> vmcnt(1): A(s),B(s) landed, A(s+1) stays in flight.
    // Recycled stages were last read at iter s-1, drained before this barrier.
#pragma unroll
    for (int s = 0; s < KSTEPS; ++s) {
        if (s == KSTEPS - 1)
            asm volatile("s_waitcnt vmcnt(0) lgkmcnt(0)" ::: "memory");
        else
            asm volatile("s_waitcnt vmcnt(1) lgkmcnt(0)" ::: "memory");
        __builtin_amdgcn_s_barrier();
        __builtin_amdgcn_sched_barrier(0);

        if (s + 1 < KSTEPS) issueB(s + 1, (s + 1) & 1);
        if (s + 2 < KSTEPS) issueA(s + 2, (s + 2) % 3);

        const int bufi = s % 3;
        const int bcur = s & 1;
        // B fragments: linear lane*16 ds_read_b128, conflict-free
        bf16x8 bfv[4];
#pragma unroll
        for (int ni = 0; ni < 4; ++ni)
            bfv[ni] = *(const bf16x8*)&bufB[bcur][(wq * 4 + ni) * 512 + lane * 8];

        const int q0 = (2 * q) ^ (r15 & 7);      // stored quarter holding j=0..3
        const int q1 = q0 ^ 1;                   // stored quarter holding j=4..7
        bf16x8 af[2];
#pragma unroll
        for (int mi = 0; mi < 2; ++mi) {
            int m = mi * 16 + r15;
            f32x4 lo = *(const f32x4*)&bufA[bufi][b][m * BK + q0 * 4];
            f32x4 hi = *(const f32x4*)&bufA[bufi][b][m * BK + q1 * 4];
            af[mi] = cvt8(lo, hi);
        }
#pragma unroll
        for (int mi = 0; mi < 2; ++mi)
#pragma unroll
            for (int ni = 0; ni < 4; ++ni)
                acc[mi][ni] = __builtin_amdgcn_mfma_f32_16x16x32_bf16(
                    af[mi], bfv[ni], acc[mi][ni], 0, 0, 0);
    }
    __syncthreads();    // all bufA/bufB reads done before epilogue aliasing writes

    const float pa = *prelu_a;

    // ================= POS epilogue (waves 0-3, acc = pos) ====================
    if (w < 4) {
#pragma unroll
        for (int mi = 0; mi < 2; ++mi) {
            const int gl = mi * 2 + (q >> 1);
            float part = 0.f;
#pragma unroll
            for (int ni = 0; ni < 4; ++ni) {
                float r0, r1, r2, r3, r4, r5, r6, r7;
#pragma unroll
                for (int r = 0; r < 4; ++r) {
                    float own = acc[mi][ni][r];
                    float oth = __shfl_xor(own, 16);
                    float lo = ((q & 1) == 0) ? own : oth;
                    float hi = ((q & 1) == 0) ? oth : own;
                    if (r == 0) { r0 = lo; r4 = hi; }
                    else if (r == 1) { r1 = lo; r5 = hi; }
                    else if (r == 2) { r2 = lo; r6 = hi; }
                    else            { r3 = lo; r7 = hi; }
                }
                int c = wq * 64 + ni * 16 + r15;
                float bg = b_gcn[c];
                float pool = 0.f, anch = 0.f;
#pragma unroll
                for (int d = 0; d < 8; ++d) {
                    const float* ar = &adjP[gl][d][0];
                    float a = bg + ar[0]*r0 + ar[1]*r1 + ar[2]*r2 + ar[3]*r3
                                 + ar[4]*r4 + ar[5]*r5 + ar[6]*r6 + ar[7]*r7;
                    float h = (a >= 0.f) ? a : pa * a;
                    if (d < 7) pool += h; else anch = h;
                }
                float pl = pool * (1.f / 7.f);
                if ((q & 1) == 0) {
                    pool_pos[gl * DOUT + c] = pl;
                    part += pl * pl;
                } else {
                    bf16 hh = (bf16)anch;
                    ahs[gl * VSTR + c] = hh;
                    als[gl * VSTR + c] = (bf16)(anch - (float)hh);
                    part += anch * anch;
                }
            }
            part += __shfl_xor(part, 8);
            part += __shfl_xor(part, 4);
            part += __shfl_xor(part, 2);
            part += __shfl_xor(part, 1);
            if (r15 == 0) atomicAdd((q & 1) ? &red[GB + gl] : &red[gl], part);
        }
    }
    __syncthreads();

    // ===== v = W_bil . anchor (3-term bf16 split MFMA), all 8 waves ==========
    // A rows duplicate the 4 anchors: row r15 -> anchor r15&3. C row q*4+r ->
    // anchor r (mod 4), identical across q -> use q==0 lanes only.
    {
        f32x4 accv[2];
        accv[0] = (f32x4){0.f, 0.f, 0.f, 0.f};
        accv[1] = (f32x4){0.f, 0.f, 0.f, 0.f};
        const int ga = (r15 & 3) * VSTR;
#pragma unroll
        for (int ks = 0; ks < 8; ++ks) {
            bf16x8 ah_f = *(const bf16x8*)(ahs + ga + ks * 32 + q * 8);
            bf16x8 al_f = *(const bf16x8*)(als + ga + ks * 32 + q * 8);
#pragma unroll
            for (int ni = 0; ni < 2; ++ni) {
                int d = w * 32 + ni * 16 + r15;
                bf16x8 bh = *(const bf16x8*)(Wh + (size_t)d * DOUT + ks * 32 + q * 8);
                bf16x8 bl = *(const bf16x8*)(Wl + (size_t)d * DOUT + ks * 32 + q * 8);
                accv[ni] = __builtin_amdgcn_mfma_f32_16x16x32_bf16(ah_f, bh, accv[ni], 0, 0, 0);
                accv[ni] = __builtin_amdgcn_mfma_f32_16x16x32_bf16(al_f, bh, accv[ni], 0, 0, 0);
                accv[ni] = __builtin_amdgcn_mfma_f32_16x16x32_bf16(ah_f, bl, accv[ni], 0, 0, 0);
            }
        }
        float sp[4] = {0.f, 0.f, 0.f, 0.f};
        if (q == 0) {
#pragma unroll
            for (int ni = 0; ni < 2; ++ni) {
                int d = w * 32 + ni * 16 + r15;
#pragma unroll
                for (int r = 0; r < 4; ++r) {
                    v_lds[r * DOUT + d] = accv[ni][r];
                    sp[r] += accv[ni][r] * pool_pos[r * DOUT + d];
                }
            }
        }
#pragma unroll
        for (int r = 0; r < 4; ++r) {
            sp[r] += __shfl_xor(sp[r], 8);
            sp[r] += __shfl_xor(sp[r], 4);
            sp[r] += __shfl_xor(sp[r], 2);
            sp[r] += __shfl_xor(sp[r], 1);
        }
        if (q == 0 && r15 == 0) {
#pragma unroll
            for (int r = 0; r < 4; ++r) atomicAdd(&red[3 * GB + r], sp[r]);
        }
    }
    __syncthreads();

    // ================= NEG epilogue (waves 4-7, acc = neg) ====================
    if (w >= 4) {
#pragma unroll
        for (int mi = 0; mi < 2; ++mi) {
            const int gl = mi * 2 + (q >> 1);
            float part = 0.f;
#pragma unroll
            for (int ni = 0; ni < 4; ++ni) {
                float r0, r1, r2, r3, r4, r5, r6, r7;
#pragma unroll
                for (int r = 0; r < 4; ++r) {
                    float own = acc[mi][ni][r];
                    float oth = __shfl_xor(own, 16);
                    float lo = ((q & 1) == 0) ? own : oth;
                    float hi = ((q & 1) == 0) ? oth : own;
                    if (r == 0) { r0 = lo; r4 = hi; }
                    else if (r == 1) { r1 = lo; r5 = hi; }
                    else if (r == 2) { r2 = lo; r6 = hi; }
                    else            { r3 = lo; r7 = hi; }
                }
                int c = wq * 64 + ni * 16 + r15;
                float bg = b_gcn[c];
                float pool = 0.f;
#pragma unroll
                for (int d = 0; d < 7; ++d) {
                    const float* ar = &adjN[gl][d][0];
                    float a = bg + ar[0]*r0 + ar[1]*r1 + ar[2]*r2 + ar[3]*r3
                                 + ar[4]*r4 + ar[5]*r5 + ar[6]*r6 + ar[7]*r7;
                    float h = (a >= 0.f) ? a : pa * a;
                    pool += h;
                }
                float pl = pool * (1.f / 7.f);
                part += ((q & 1) == 0) ? pl * v_lds[gl * DOUT + c] : pl * pl;
            }
            part += __shfl_xor(part, 8);
            part += __shfl_xor(part, 4);
            part += __shfl_xor(part, 2);
            part += __shfl_xor(part, 1);
            if (r15 == 0) atomicAdd((q & 1) ? &red[2 * GB + gl] : &red[4 * GB + gl], part);
        }
    }
    __syncthreads();

    // ================= finalize ===============================================
    if (t < GB) {
        float np = fmaxf(sqrtf(red[t]), EPSN);
        float na = fmaxf(sqrtf(red[GB + t]), EPSN);
        float nn = fmaxf(sqrtf(red[2 * GB + t]), EPSN);
        float bb = b_bil[0];
        out[wg * GB + t]        = red[3 * GB + t] / (np * na) + bb;
        out[NBLK + wg * GB + t] = red[4 * GB + t] / (nn * na) + bb;
    }
}

extern "C" void kernel_launch(void* const* d_in, const int* in_sizes, int n_in,
                              void* d_out, int out_size, void* d_ws, size_t ws_size,
                              hipStream_t stream) {
    const float* pos_x   = (const float*)d_in[0];
    const float* neg_x   = (const float*)d_in[1];
    const int*   pos_src = (const int*)d_in[2];
    const int*   pos_dst = (const int*)d_in[3];
    const float* pos_w   = (const float*)d_in[4];
    const int*   neg_src = (const int*)d_in[5];
    const int*   neg_dst = (const int*)d_in[6];
    const float* neg_w   = (const float*)d_in[7];
    const float* W_gcn   = (const float*)d_in[8];
    const float* b_gcn   = (const float*)d_in[9];
    const float* prelu_a = (const float*)d_in[10];
    const float* W_bil   = (const float*)d_in[11];
    const float* b_bil   = (const float*)d_in[12];
    float* outp = (float*)d_out;

    bf16* WtImg = (bf16*)d_ws;              // 256 KB (fragment-order)
    bf16* Wh    = WtImg + DIN * DOUT;       // 128 KB
    bf16* Wl    = Wh + DOUT * DOUT;         // 128 KB

    prep_kernel<<<(DIN * DOUT + DOUT * DOUT) / 256, 256, 0, stream>>>(W_gcn, W_bil, WtImg, Wh, Wl);
    cola_fused8<<<NBLK / GB, 512, 0, stream>>>(
        pos_x, neg_x, pos_src, pos_dst, pos_w, neg_src, neg_dst, neg_w,
        WtImg, Wh, Wl, b_gcn, prelu_a, b_bil, outp);
}